// Round 14
// baseline (407.782 us; speedup 1.0000x reference)
//
#include <hip/hip_runtime.h>

constexpr int TT = 512;    // timesteps
constexpr int BB = 256;    // batch
constexpr int HH = 128;    // hidden = embed
constexpr int VV = 32000;  // vocab

typedef _Float16 h2 __attribute__((ext_vector_type(2)));
typedef _Float16 f16x4 __attribute__((ext_vector_type(4)));
typedef _Float16 f16x8 __attribute__((ext_vector_type(8)));
typedef float f32x4 __attribute__((ext_vector_type(4)));

struct __align__(16) H2x4 { h2 a, b, c, d; };

__device__ __forceinline__ h2 pkrtz(float a, float b) {
  return __builtin_bit_cast(h2, __builtin_amdgcn_cvt_pkrtz(a, b));
}
__device__ __forceinline__ float fexp2(float x) {
  return __builtin_amdgcn_exp2f(x);
}
__device__ __forceinline__ float frcp(float x) {
  return __builtin_amdgcn_rcpf(x);
}
// quad_perm DPP: 0xB1 = [1,0,3,2] (xor1), 0x4E = [2,3,0,1] (xor2)
template <int CTRL>
__device__ __forceinline__ float qmov(float v) {
  return __builtin_bit_cast(
      float, __builtin_amdgcn_mov_dpp(__builtin_bit_cast(int, v), CTRL, 0xf,
                                      0xf, true));
}

// Gate pre-scales folded into weights so activations are exp2-direct:
//   g in {i,f,o}: a = -x*log2e  -> exp2(a) = e^-x   (sigmoid via rcp)
//   g == c      : a = 2x*log2e  -> exp2(a) = e^{2x} (tanh via rcp)
constexpr float SC_SIG = -1.4426950408889634f;
constexpr float SC_TANH = 2.8853900817779268f;

// Fused prep (R14: transpose back here — R13 proved co-residing it with the
// recurrence costs 17 µs of interference vs ~4 µs serial):
//   blocks [0,512): gate-pack Wct[n=4u+g][k] f16 (k 0..127 e-part,
//     128..255 h-part) + bcat[n] (scaled bias).
//   blocks [512, 637): Wout fp32 -> Wt f16 in chunk-interleaved MFMA layout
//     [v16-block][kchunk][v%16][8f16] (R13-verified; makes lstm_out's B-frag
//     loads 1KB-contiguous per wave).
__global__ __launch_bounds__(256, 4) void prep(
    const float* __restrict__ Wi, const float* __restrict__ bi,
    const float* __restrict__ Wf, const float* __restrict__ bf,
    const float* __restrict__ Wc, const float* __restrict__ bc,
    const float* __restrict__ Wo, const float* __restrict__ bo,
    _Float16* __restrict__ Wct, float* __restrict__ bcat,
    const float* __restrict__ Wout, _Float16* __restrict__ Wt) {
  if (blockIdx.x < 512) {
    const int n = blockIdx.x;  // 0..511
    const int g = n & 3;
    const int u = n >> 2;
    const float* Wg = (g == 0) ? Wi : (g == 1) ? Wf : (g == 2) ? Wc : Wo;
    const float* bg = (g == 0) ? bi : (g == 1) ? bf : (g == 2) ? bc : bo;
    const float sc = (g == 2) ? SC_TANH : SC_SIG;
    const int k = threadIdx.x;  // 0..255
    Wct[(size_t)n * 256 + k] = (_Float16)(Wg[(size_t)k * HH + u] * sc);
    if (k == 0) bcat[n] = bg[u] * sc;
  } else {
    const int v = (blockIdx.x - 512) * 256 + threadIdx.x;
#pragma unroll 1
    for (int kc = 0; kc < 16; ++kc) {
      float f[8];
#pragma unroll
      for (int i = 0; i < 8; ++i) f[i] = Wout[(size_t)(kc * 8 + i) * VV + v];
      H2x4 q;
      q.a = pkrtz(f[0], f[1]);
      q.b = pkrtz(f[2], f[3]);
      q.c = pkrtz(f[4], f[5]);
      q.d = pkrtz(f[6], f[7]);
      *(f16x8*)(Wt + ((size_t)(v >> 4) * 256 + kc * 16 + (v & 15)) * 8) =
          __builtin_bit_cast(f16x8, q);
    }
  }
}

// R14 = the proven 335 µs lstm_rec core (R4/R12 signature: VGPR 96,
// MfmaUtil ~38, VALUBusy ~33), clean 256-block grid (no filler — R13 showed
// 17 µs interference), chunk-interleaved hbf final write (R13-verified).
// One block per batch element, 512 threads = 8 waves, 2/SIMD.
// Wave w owns gate-rows [64w, 64w+64) = 4 row-tiles (nt).
// Step: B = h(t-1) broadcast to 16 cols (wave-uniform ds_read_b128 x4);
//   16 MFMA (4 indep nt-chains); lane extracts ONE scalar gate g=n16&3 of
//   unit u=16w+4*(n16>>2)+quad (15 cndmask), activates (1 exp2 + 1 rcp);
//   3 quad-perm DPPs hand f,c~,o to owner lane (g==0): cst update + tanh.
//   ONE barrier per step.
// Structural note (R2-R11 factorial): the per-step barrier phase-locks all
// waves; MFMA (~620 cyc/SIMD), VALU (~520), LDS/latency (~430) do not
// overlap; no decomposition tried (dot2 x3, dual-pipe, rotor, 1/2/4
// waves/SIMD) beats this. Step floor ~1570 cyc = ~335 µs for 512 steps.
__global__ __launch_bounds__(512, 2) void lstm_rec(
    const int* __restrict__ x, const float* __restrict__ emb,
    const _Float16* __restrict__ Wct, const float* __restrict__ bcat,
    _Float16* __restrict__ hbf) {
  const int b = blockIdx.x;
  const int tid = threadIdx.x;
  const int w = tid >> 6;   // wave 0..7
  const int l = tid & 63;
  const int n16 = l & 15;
  const int quad = l >> 4;
  const int g = n16 & 3;                    // lane's gate (0=i,1=f,2=c,3=o)
  const int nts = n16 >> 2;                 // lane's nt slab
  const int u = 16 * w + 4 * nts + quad;    // lane's unit
  const int xcol = 4 * u + g;               // lane's e-proj column

  __shared__ int xrow[TT];
  __shared__ __align__(16) _Float16 comb[2][HH];   // h double-buffer
  __shared__ __align__(16) _Float16 xch[64][516];  // e-proj chunk

  xrow[tid] = x[(size_t)b * TT + tid];
  if (tid < HH) comb[0][tid] = (_Float16)0.f;

  // ---- h-part A-frags: wh[nt][ks], rows n = 64w + 16nt + n16 (pinned)
  f16x8 wh[4][4];
#pragma unroll
  for (int nt = 0; nt < 4; ++nt)
#pragma unroll
    for (int ks = 0; ks < 4; ++ks)
      wh[nt][ks] = *(const f16x8*)(Wct +
                                   (size_t)(64 * w + nt * 16 + n16) * 256 +
                                   128 + ks * 32 + quad * 8);

  // ---- e-part A-frags + scaled bias
  f16x8 wfx[4][4];
  f32x4 biasr[4];
#pragma unroll
  for (int nt = 0; nt < 4; ++nt) {
#pragma unroll
    for (int ks = 0; ks < 4; ++ks)
      wfx[nt][ks] = *(const f16x8*)(Wct +
                                    (size_t)(64 * w + nt * 16 + n16) * 256 +
                                    ks * 32 + quad * 8);
    biasr[nt] = *(const f32x4*)(bcat + 64 * w + nt * 16 + quad * 4);
  }

  // per-lane activation constants: act = gam * rcp(1 + exp2(a)) + del
  const float gam = (g == 2) ? -2.f : 1.f;
  const float del = (g == 2) ? 1.f : 0.f;

  const f32x4 ZR4 = {0.f, 0.f, 0.f, 0.f};

  float cst = 0.f;  // valid on owner lanes (g==0) only
  float hv = 0.f;
  int buf = 0;

  __syncthreads();  // xrow + comb[0] visible

  for (int c = 0; c < 8; ++c) {
    // ---- MFMA e-projection for t in [64c, 64c+64): xch[t&63][n], bias as C
#pragma unroll 2
    for (int tt = 0; tt < 4; ++tt) {
      const int vid = xrow[c * 64 + tt * 16 + n16];
      const float* ep = emb + (size_t)vid * HH + quad * 8;
      f16x8 ef[4];
#pragma unroll
      for (int ks = 0; ks < 4; ++ks) {
        const float4 e0 = *(const float4*)(ep + ks * 32);
        const float4 e1 = *(const float4*)(ep + ks * 32 + 4);
        H2x4 q;
        q.a = pkrtz(e0.x, e0.y);
        q.b = pkrtz(e0.z, e0.w);
        q.c = pkrtz(e1.x, e1.y);
        q.d = pkrtz(e1.z, e1.w);
        ef[ks] = __builtin_bit_cast(f16x8, q);
      }
      f32x4 acc[4];
#pragma unroll
      for (int nt = 0; nt < 4; ++nt)
        acc[nt] = __builtin_amdgcn_mfma_f32_16x16x32_f16(wfx[nt][0], ef[0],
                                                         biasr[nt], 0, 0, 0);
#pragma unroll
      for (int ks = 1; ks < 4; ++ks)
#pragma unroll
        for (int nt = 0; nt < 4; ++nt)
          acc[nt] = __builtin_amdgcn_mfma_f32_16x16x32_f16(wfx[nt][ks], ef[ks],
                                                           acc[nt], 0, 0, 0);
#pragma unroll
      for (int nt = 0; nt < 4; ++nt) {
        _Float16* dst = &xch[tt * 16 + n16][64 * w + nt * 16 + quad * 4];
        *(h2*)dst = pkrtz(acc[nt][0], acc[nt][1]);
        *(h2*)(dst + 2) = pkrtz(acc[nt][2], acc[nt][3]);
      }
    }
    __syncthreads();  // xch ready

    // ---- 64 recurrence steps
#pragma unroll 2
    for (int tl = 0; tl < 64; ++tl) {
      // lane's own-gate e-projection scalar
      const float xe = (float)xch[tl][xcol];

      // B frags: h(t-1) broadcast to all 16 cols (wave-uniform reads)
      const _Float16* cb = comb[buf];
      f16x8 hb[4];
#pragma unroll
      for (int ks = 0; ks < 4; ++ks)
        hb[ks] = *(const f16x8*)(cb + ks * 32 + quad * 8);

      f32x4 acc[4];
#pragma unroll
      for (int nt = 0; nt < 4; ++nt)
        acc[nt] = __builtin_amdgcn_mfma_f32_16x16x32_f16(wh[nt][0], hb[0],
                                                         ZR4, 0, 0, 0);
#pragma unroll
      for (int ks = 1; ks < 4; ++ks)
#pragma unroll
        for (int nt = 0; nt < 4; ++nt)
          acc[nt] = __builtin_amdgcn_mfma_f32_16x16x32_f16(wh[nt][ks], hb[ks],
                                                           acc[nt], 0, 0, 0);

      // extract lane's single gate scalar: nt tree (12) + r tree (3)
      const bool s4 = (n16 & 4) != 0;
      const bool s8 = (n16 & 8) != 0;
      const f32x4 t01 = s4 ? acc[1] : acc[0];
      const f32x4 t23 = s4 ? acc[3] : acc[2];
      const f32x4 avq = s8 ? t23 : t01;
      const bool s1 = (n16 & 1) != 0;
      const bool s2 = (n16 & 2) != 0;
      const float r01 = s1 ? avq[1] : avq[0];
      const float r23 = s1 ? avq[3] : avq[2];
      const float a = (s2 ? r23 : r01) + xe;  // pre-activation (scaled)

      // own-gate activation: 1 exp2 + 1 rcp per wave-lane
      const float act = gam * frcp(1.f + fexp2(a)) + del;

      // deliver f, c~, o to the owner lane (g==0) via quad-perm DPP
      const float x1 = qmov<0xB1>(act);  // owner <- f
      const float x2 = qmov<0x4E>(act);  // owner <- c~
      const float x3 = qmov<0x4E>(x1);   // owner <- o

      // owner lanes: cst/h update (other lanes compute garbage, never used)
      cst = x1 * cst + act * x2;  // f*cst + i*c~
      const float th = 1.f - 2.f * frcp(1.f + fexp2(cst * SC_TANH));
      hv = x3 * th;

      if (g == 0) comb[buf ^ 1][u] = (_Float16)hv;
      __syncthreads();  // h(t) visible; all reads of comb[buf] done
      buf ^= 1;
    }
  }
  // chunk-interleaved hbf: C(bat,kc) = (bat>>4)*256 + kc*16 + (bat&15),
  // elem u&7 within the 8-f16 chunk (kc = u>>3).
  if (g == 0)
    hbf[((size_t)(b >> 4) * 256 + (u >> 3) * 16 + (b & 15)) * 8 + (u & 7)] =
        (_Float16)hv;
}

// logits = h @ Wout + bout via f16 MFMA (R13-verified). Both operand
// matrices in chunk-interleaved layout [row16][kchunk][row%16][8f16]: each
// frag load reads 64 CONSECUTIVE 16B chunks per wave (1KB contiguous).
// Block: 4 waves; tile [64 bat x 128 v]; wave: [64 bat x 32 v].
__global__ __launch_bounds__(256, 4) void lstm_out(
    const _Float16* __restrict__ Wt, const _Float16* __restrict__ hbf,
    const float* __restrict__ bout, float* __restrict__ out) {
  const int tid = threadIdx.x;
  const int wv = tid >> 6;
  const int lane = tid & 63;
  const int vblk = blockIdx.x % 250;
  const int batblk = blockIdx.x / 250;
  const int n16 = lane & 15;
  const int quad = lane >> 4;
  const int vbase = vblk * 128 + wv * 32;
  const int batbase = batblk * 64;

  f32x4 acc[4][2] = {};
#pragma unroll
  for (int ks = 0; ks < 4; ++ks) {
    f16x8 a[4], bf_[2];
#pragma unroll
    for (int mt = 0; mt < 4; ++mt)
      a[mt] = *(const f16x8*)(hbf +
                              (((size_t)(batblk * 4 + mt) << 8) + (ks << 6) +
                               lane) * 8);
#pragma unroll
    for (int vt = 0; vt < 2; ++vt)
      bf_[vt] = *(const f16x8*)(Wt +
                                (((size_t)(vblk * 8 + wv * 2 + vt) << 8) +
                                 (ks << 6) + lane) * 8);
#pragma unroll
    for (int mt = 0; mt < 4; ++mt)
#pragma unroll
      for (int vt = 0; vt < 2; ++vt)
        acc[mt][vt] = __builtin_amdgcn_mfma_f32_16x16x32_f16(a[mt], bf_[vt],
                                                             acc[mt][vt], 0, 0, 0);
  }
#pragma unroll
  for (int vt = 0; vt < 2; ++vt) {
    const int v = vbase + vt * 16 + n16;
    const float bv = bout[v];
#pragma unroll
    for (int mt = 0; mt < 4; ++mt) {
#pragma unroll
      for (int r = 0; r < 4; ++r) {
        const int bat = batbase + mt * 16 + quad * 4 + r;
        out[(size_t)bat * VV + v] = acc[mt][vt][r] + bv;
      }
    }
  }
}

extern "C" void kernel_launch(void* const* d_in, const int* in_sizes, int n_in,
                              void* d_out, int out_size, void* d_ws,
                              size_t ws_size, hipStream_t stream) {
  const int* x = (const int*)d_in[0];
  const float* emb = (const float*)d_in[1];
  const float* Wi = (const float*)d_in[2];
  const float* bi = (const float*)d_in[3];
  const float* Wf = (const float*)d_in[4];
  const float* bf = (const float*)d_in[5];
  const float* Wc = (const float*)d_in[6];
  const float* bc = (const float*)d_in[7];
  const float* Wo = (const float*)d_in[8];
  const float* bo = (const float*)d_in[9];
  const float* Wout = (const float*)d_in[10];
  const float* bout = (const float*)d_in[11];
  float* out = (float*)d_out;

  _Float16* Wt = (_Float16*)d_ws;          // 32000*128 f16 = 8.192 MB
  _Float16* hbf = Wt + (size_t)VV * HH;    // 256*128 f16  = 64 KB
  _Float16* Wct = hbf + (size_t)BB * HH;   // 512*256 f16  = 256 KB
  float* bcat = (float*)(Wct + 512 * 256); // 512 f32      = 2 KB

  prep<<<512 + VV / 256, 256, 0, stream>>>(Wi, bi, Wf, bf, Wc, bc, Wo, bo,
                                           Wct, bcat, Wout, Wt);
  lstm_rec<<<BB, 512, 0, stream>>>(x, emb, Wct, bcat, hbf);
  lstm_out<<<(VV / 128) * (BB / 64), 256, 0, stream>>>(Wt, hbf, bout, out);
}